// Round 3
// 1115.113 us; speedup vs baseline: 1.0349x; 1.0349x over previous
//
#include <hip/hip_runtime.h>
#include <hip/hip_bf16.h>
#include <stdint.h>

#define BB 4
#define HH 12
#define TT 2048
#define DD 64
#define EE 768
#define BT (BB*TT)          // 8192
#define NQKV (3*EE)         // 2304

typedef __attribute__((ext_vector_type(8))) short bf16x8;
typedef __attribute__((ext_vector_type(4))) float f32x4;

__device__ __forceinline__ unsigned short f2bf(float f){
  union { float f; unsigned int u; } x; x.f = f;
  unsigned int u = x.u;
  unsigned int r = (u + 0x7fffu + ((u >> 16) & 1u)) >> 16;
  return (unsigned short)r;
}

// ---------------- f32 -> bf16 convert (n divisible by 4) ----------------
__global__ void cvt_bf16(const float* __restrict__ src, unsigned short* __restrict__ dst, int n){
  int i = (blockIdx.x*blockDim.x + threadIdx.x)*4;
  if (i < n){
    float4 v = *(const float4*)&src[i];
    ushort4 o;
    o.x = f2bf(v.x); o.y = f2bf(v.y); o.z = f2bf(v.z); o.w = f2bf(v.w);
    *(ushort4*)&dst[i] = o;
  }
}

// ---------------- weight transpose + convert (768x768, f32 -> bf16^T) ----------------
__global__ void transpose_cvt_768(const float* __restrict__ src,
                                  unsigned short* __restrict__ dst){
  __shared__ float tile[32][33];
  int bx = blockIdx.x*32, by = blockIdx.y*32;
  int tx = threadIdx.x, ty = threadIdx.y;   // 32 x 8
  #pragma unroll
  for (int i=0;i<32;i+=8) tile[ty+i][tx] = src[(size_t)(by+ty+i)*EE + bx+tx];
  __syncthreads();
  #pragma unroll
  for (int i=0;i<32;i+=8) dst[(size_t)(bx+ty+i)*EE + by+tx] = f2bf(tile[tx][ty+i]);
}

// ---------------- 128x128 MFMA GEMM core (A row-major MxK bf16, Bt row-major NxK bf16) ----------------
__device__ __forceinline__ void gemm_core_128(
    const unsigned short* __restrict__ A, const unsigned short* __restrict__ Bt,
    int K, int mBase, int nBase,
    unsigned short* Alds, unsigned short* Blds,
    f32x4 acc[4][4])
{
  const int tid = threadIdx.x;
  const int lane = tid & 63, wave = tid >> 6;
  const int wm = wave & 1, wn = wave >> 1;
  const int ln15 = lane & 15, quad = lane >> 4;
  #pragma unroll
  for (int mt=0; mt<4; ++mt)
    #pragma unroll
    for (int nt=0; nt<4; ++nt)
      acc[mt][nt] = (f32x4){0.f,0.f,0.f,0.f};

  for (int k0=0; k0<K; k0+=32){
    #pragma unroll
    for (int i=0;i<2;i++){
      int idx = tid + i*256;
      int r = idx >> 2, seg = idx & 3;
      *(uint4*)&Alds[r*40 + seg*8] = *(const uint4*)&A[(size_t)(mBase + r)*K + k0 + seg*8];
      *(uint4*)&Blds[r*40 + seg*8] = *(const uint4*)&Bt[(size_t)(nBase + r)*K + k0 + seg*8];
    }
    __syncthreads();
    bf16x8 af[4], bfr[4];
    #pragma unroll
    for (int mt=0;mt<4;++mt) af[mt]  = *(const bf16x8*)&Alds[(wm*64 + mt*16 + ln15)*40 + quad*8];
    #pragma unroll
    for (int nt=0;nt<4;++nt) bfr[nt] = *(const bf16x8*)&Blds[(wn*64 + nt*16 + ln15)*40 + quad*8];
    #pragma unroll
    for (int mt=0;mt<4;++mt)
      #pragma unroll
      for (int nt=0;nt<4;++nt)
        acc[mt][nt] = __builtin_amdgcn_mfma_f32_16x16x32_bf16(af[mt], bfr[nt], acc[mt][nt], 0,0,0);
    __syncthreads();
  }
}

// ---------------- QKV projection -> scatter to q/k/v ws (bf16) ----------------
// Q is pre-scaled by 0.125*log2(e) so attention can use exp2 directly.
#define QSCALE 0.18033688f
__global__ __launch_bounds__(256,2) void gemm_qkv(
    const unsigned short* __restrict__ x, const unsigned short* __restrict__ WtQKV,
    const float* __restrict__ bq, const float* __restrict__ bk,
    const float* __restrict__ bv,
    unsigned short* __restrict__ q_ws, unsigned short* __restrict__ k_ws,
    unsigned short* __restrict__ v_ws)
{
  __shared__ unsigned short Alds[128*40];
  __shared__ unsigned short Blds[128*40];
  const int mBase = blockIdx.y*128, nBase = blockIdx.x*128;
  f32x4 acc[4][4];
  gemm_core_128(x, WtQKV, EE, mBase, nBase, Alds, Blds, acc);

  const int tid = threadIdx.x, lane = tid&63, wave = tid>>6;
  const int wm = wave&1, wn = wave>>1, ln15 = lane&15, quad = lane>>4;
  const int which = nBase / EE;   // wave-uniform: 768 % 128 == 0
  const float* bias = (which==0) ? bq : ((which==1) ? bk : bv);
  const float sc = (which==0) ? QSCALE : 1.0f;
  #pragma unroll
  for (int nt=0;nt<4;++nt){
    int col = nBase + wn*64 + nt*16 + ln15;
    int n0 = col - which*EE;
    int h = n0 >> 6, d = n0 & 63;
    float bsv = bias[n0];
    #pragma unroll
    for (int mt=0;mt<4;++mt){
      #pragma unroll
      for (int reg=0;reg<4;++reg){
        int row = mBase + wm*64 + mt*16 + quad*4 + reg;
        int b = row >> 11, t = row & 2047;
        unsigned short o = f2bf((acc[mt][nt][reg] + bsv)*sc);
        if (which==0)      q_ws[((size_t)(b*HH + h)*TT + t)*DD + d] = o;
        else if (which==1) k_ws[((size_t)(b*HH + h)*TT + t)*DD + d] = o;
        else               v_ws[((size_t)(b*HH + h)*DD + d)*TT + t] = o;  // V stored [B,H,D,T]
      }
    }
  }
}

// ---------------- output projection: out(f32) = y_ws(bf16) @ WoT + bo ----------------
__global__ __launch_bounds__(256,2) void gemm_proj(
    const unsigned short* __restrict__ yin, const unsigned short* __restrict__ WoT,
    const float* __restrict__ bo, float* __restrict__ out)
{
  __shared__ unsigned short Alds[128*40];
  __shared__ unsigned short Blds[128*40];
  const int mBase = blockIdx.y*128, nBase = blockIdx.x*128;
  f32x4 acc[4][4];
  gemm_core_128(yin, WoT, EE, mBase, nBase, Alds, Blds, acc);

  const int tid = threadIdx.x, lane = tid&63, wave = tid>>6;
  const int wm = wave&1, wn = wave>>1, ln15 = lane&15, quad = lane>>4;
  #pragma unroll
  for (int nt=0;nt<4;++nt){
    int col = nBase + wn*64 + nt*16 + ln15;
    float bsv = bo[col];
    #pragma unroll
    for (int mt=0;mt<4;++mt){
      #pragma unroll
      for (int reg=0;reg<4;++reg){
        int row = mBase + wm*64 + mt*16 + quad*4 + reg;
        out[(size_t)row*EE + col] = acc[mt][nt][reg] + bsv;
      }
    }
  }
}

// ---------------- two-pass causal attention, 64 q-rows per block ----------------
// Q pre-scaled by 0.125*log2e -> scores are exp2 arguments directly.
// Masked entries use a finite sentinel (-3e4): exp2 -> 0 exactly.
//  * double-buffered K/V LDS, register prefetch of kt+1 under compute of kt
//    -> ONE __syncthreads per kt-tile
//  * pass-A cross-lane reduce hoisted out of the kt loop (per-lane partials)
//  * Ps is wave-private -> no barrier between Ps write and read
//  * XCD-aware block swizzle: sid&7 selects head-group so each XCD's L2
//    holds only 6 heads' K/V (~3 MB < 4 MB)
__global__ __launch_bounds__(256,2) void attn_kernel(
    const unsigned short* __restrict__ q_ws, const unsigned short* __restrict__ k_ws,
    const unsigned short* __restrict__ v_ws, float* __restrict__ att,
    unsigned short* __restrict__ y_ws)
{
  const int sid = blockIdx.x;              // 0..1535
  const int qt  = (sid >> 3) & 31;         // q-tile
  const int bh  = (sid & 7) + ((sid >> 8) << 3);   // bijective: xcd + 8*group
  const int b  = bh / HH, h = bh - b*HH;
  const int tid = threadIdx.x, lane = tid&63, wave = tid>>6;
  const int quad = lane>>4, ln15 = lane&15;

  __shared__ unsigned short Qs[64*72];
  __shared__ unsigned short Ks[2][64*72];
  __shared__ unsigned short Vts[2][64*72];
  __shared__ unsigned short Ps[4*16*72];

  const unsigned short* Qg = q_ws + ((size_t)bh*TT + qt*64)*DD;
  const unsigned short* Kg = k_ws + (size_t)bh*TT*DD;
  const unsigned short* Vg = v_ws + (size_t)bh*DD*TT;   // [D][T]
  float* attb = att + ((size_t)bh*TT + (size_t)qt*64)*TT;

  const int r0 = tid>>3, sg = tid&7;   // staging: row r0 / r0+32, 16B segment sg
  const int r1 = r0 + 32;

  // issue K tile-0 prefetch early (overlaps Q staging + barrier)
  uint4 ka0 = *(const uint4*)&Kg[(size_t)r0*DD + sg*8];
  uint4 ka1 = *(const uint4*)&Kg[(size_t)r1*DD + sg*8];

  // stage Q (64x64)
  *(uint4*)&Qs[r0*72 + sg*8] = *(const uint4*)&Qg[(size_t)r0*DD + sg*8];
  *(uint4*)&Qs[r1*72 + sg*8] = *(const uint4*)&Qg[(size_t)r1*DD + sg*8];
  __syncthreads();
  bf16x8 aq0 = *(const bf16x8*)&Qs[(wave*16+ln15)*72 + quad*8];
  bf16x8 aq1 = *(const bf16x8*)&Qs[(wave*16+ln15)*72 + 32 + quad*8];

  const float NEG = -30000.0f;      // finite mask sentinel (exp2 -> exactly 0)
  const int qrow0 = qt*64 + wave*16 + quad*4;   // + reg = global q row within head

  // ---- PASS A: per-lane partial row sums of exp2(s); reduce once after loop ----
  float lp[4] = {0.f,0.f,0.f,0.f};
  for (int kt=0; kt<=qt; ++kt){
    unsigned short* Kb = Ks[kt&1];
    *(uint4*)&Kb[r0*72 + sg*8] = ka0;
    *(uint4*)&Kb[r1*72 + sg*8] = ka1;
    __syncthreads();
    if (kt < qt){   // prefetch next tile under this tile's compute
      ka0 = *(const uint4*)&Kg[(size_t)((kt+1)*64+r0)*DD + sg*8];
      ka1 = *(const uint4*)&Kg[(size_t)((kt+1)*64+r1)*DD + sg*8];
    }
    f32x4 s[4];
    #pragma unroll
    for (int nt=0;nt<4;++nt){
      s[nt] = (f32x4){0.f,0.f,0.f,0.f};
      bf16x8 bk0 = *(const bf16x8*)&Kb[(nt*16+ln15)*72 + quad*8];
      bf16x8 bk1 = *(const bf16x8*)&Kb[(nt*16+ln15)*72 + 32 + quad*8];
      s[nt] = __builtin_amdgcn_mfma_f32_16x16x32_bf16(aq0, bk0, s[nt], 0,0,0);
      s[nt] = __builtin_amdgcn_mfma_f32_16x16x32_bf16(aq1, bk1, s[nt], 0,0,0);
    }
    const bool diag = (kt==qt);
    #pragma unroll
    for (int reg=0;reg<4;++reg){
      #pragma unroll
      for (int nt=0;nt<4;++nt){
        float v = s[nt][reg];
        if (diag && (kt*64 + nt*16 + ln15) > qrow0+reg) v = NEG;
        lp[reg] += exp2f(v);
      }
    }
    // no end-of-loop barrier: double buffer + top barrier covers WAR
  }
  float rl[4];
  #pragma unroll
  for (int r=0;r<4;++r){
    float ss = lp[r];
    ss += __shfl_xor(ss, 1);
    ss += __shfl_xor(ss, 2);
    ss += __shfl_xor(ss, 4);
    ss += __shfl_xor(ss, 8);
    rl[r] = 1.f / ss;
  }

  // ---- PASS B: normalized P -> att (f32) + accumulate Y ----
  f32x4 yacc[4];
  #pragma unroll
  for (int nt=0;nt<4;++nt) yacc[nt] = (f32x4){0.f,0.f,0.f,0.f};

  uint4 kb0 = *(const uint4*)&Kg[(size_t)r0*DD + sg*8];
  uint4 kb1 = *(const uint4*)&Kg[(size_t)r1*DD + sg*8];
  uint4 vb0 = *(const uint4*)&Vg[(size_t)r0*TT + sg*8];
  uint4 vb1 = *(const uint4*)&Vg[(size_t)r1*TT + sg*8];
  __syncthreads();   // separate pass-A LDS reads from pass-B buffer writes

  for (int kt=0; kt<=qt; ++kt){
    unsigned short* Kb = Ks[kt&1];
    unsigned short* Vb = Vts[kt&1];
    *(uint4*)&Kb[r0*72 + sg*8] = kb0;
    *(uint4*)&Kb[r1*72 + sg*8] = kb1;
    *(uint4*)&Vb[r0*72 + sg*8] = vb0;
    *(uint4*)&Vb[r1*72 + sg*8] = vb1;
    __syncthreads();
    if (kt < qt){   // prefetch next K/V under this tile's compute
      kb0 = *(const uint4*)&Kg[(size_t)((kt+1)*64+r0)*DD + sg*8];
      kb1 = *(const uint4*)&Kg[(size_t)((kt+1)*64+r1)*DD + sg*8];
      vb0 = *(const uint4*)&Vg[(size_t)r0*TT + (kt+1)*64 + sg*8];
      vb1 = *(const uint4*)&Vg[(size_t)r1*TT + (kt+1)*64 + sg*8];
    }
    f32x4 s[4];
    #pragma unroll
    for (int nt=0;nt<4;++nt){
      s[nt] = (f32x4){0.f,0.f,0.f,0.f};
      bf16x8 bk0 = *(const bf16x8*)&Kb[(nt*16+ln15)*72 + quad*8];
      bf16x8 bk1 = *(const bf16x8*)&Kb[(nt*16+ln15)*72 + 32 + quad*8];
      s[nt] = __builtin_amdgcn_mfma_f32_16x16x32_bf16(aq0, bk0, s[nt], 0,0,0);
      s[nt] = __builtin_amdgcn_mfma_f32_16x16x32_bf16(aq1, bk1, s[nt], 0,0,0);
    }
    const bool diag = (kt==qt);
    #pragma unroll
    for (int nt=0;nt<4;++nt){
      int key = kt*64 + nt*16 + ln15;
      #pragma unroll
      for (int reg=0;reg<4;++reg){
        float v = s[nt][reg];
        if (diag && key > qrow0+reg) v = NEG;
        float p = exp2f(v)*rl[reg];
        attb[(size_t)(wave*16 + quad*4 + reg)*TT + key] = p;
        Ps[wave*1152 + (quad*4+reg)*72 + nt*16 + ln15] = f2bf(p);
      }
    }
    // Ps rows are wave-private: same-wave LDS ordering suffices, no barrier
    bf16x8 ap0 = *(const bf16x8*)&Ps[(wave*16+ln15)*72 + quad*8];
    bf16x8 ap1 = *(const bf16x8*)&Ps[(wave*16+ln15)*72 + 32 + quad*8];
    #pragma unroll
    for (int nt=0;nt<4;++nt){
      bf16x8 bv0 = *(const bf16x8*)&Vb[(nt*16+ln15)*72 + quad*8];
      bf16x8 bv1 = *(const bf16x8*)&Vb[(nt*16+ln15)*72 + 32 + quad*8];
      yacc[nt] = __builtin_amdgcn_mfma_f32_16x16x32_bf16(ap0, bv0, yacc[nt], 0,0,0);
      yacc[nt] = __builtin_amdgcn_mfma_f32_16x16x32_bf16(ap1, bv1, yacc[nt], 0,0,0);
    }
    // no end-of-loop barrier
  }

  // zero the strictly-upper region of this q-stripe (f32)
  {
    int wstart = (qt+1)*64;
    int r = tid>>2;
    float4 z = make_float4(0.f,0.f,0.f,0.f);
    for (int c = wstart + (tid&3)*4; c < TT; c += 16)
      *(float4*)&attb[(size_t)r*TT + c] = z;
  }

  // write y tile into y_ws [B*T, E] (bf16)
  #pragma unroll
  for (int nt=0;nt<4;++nt){
    #pragma unroll
    for (int reg=0;reg<4;++reg){
      int t = qt*64 + wave*16 + quad*4 + reg;
      size_t row = (size_t)b*TT + t;
      int col = h*DD + nt*16 + ln15;
      y_ws[row*EE + col] = f2bf(yacc[nt][reg]);
    }
  }
}

extern "C" void kernel_launch(void* const* d_in, const int* in_sizes, int n_in,
                              void* d_out, int out_size, void* d_ws, size_t ws_size,
                              hipStream_t stream){
  (void)in_sizes; (void)n_in; (void)out_size; (void)ws_size;
  const float* x  = (const float*)d_in[0];
  const float* Wq = (const float*)d_in[1];
  const float* bq = (const float*)d_in[2];
  const float* Wk = (const float*)d_in[3];
  const float* bk = (const float*)d_in[4];
  const float* Wv = (const float*)d_in[5];
  const float* bv = (const float*)d_in[6];
  const float* Wo = (const float*)d_in[7];
  const float* bo = (const float*)d_in[8];
  // d_in[9] = attn_mask (int32, exactly tril) — causality hard-coded.

  float* out = (float*)d_out;
  float* y_out   = out;                          // [4,2048,768] f32
  float* att_out = out + (size_t)BT*EE;          // [4,12,2048,2048] f32

  unsigned short* ws = (unsigned short*)d_ws;
  unsigned short* x_bf   = ws;                                  // 8192*768
  unsigned short* WtQKV  = x_bf  + (size_t)BT*EE;               // 2304*768
  unsigned short* WoT    = WtQKV + (size_t)NQKV*EE;             // 768*768
  unsigned short* q_ws   = WoT   + (size_t)EE*EE;               // [B,H,T,D] (pre-scaled)
  unsigned short* k_ws   = q_ws  + (size_t)BB*HH*TT*DD;
  unsigned short* v_ws   = k_ws  + (size_t)BB*HH*TT*DD;         // [B,H,D,T]
  unsigned short* y_ws   = v_ws  + (size_t)BB*HH*TT*DD;         // [B*T, E]

  cvt_bf16<<<(BT*EE)/(256*4), 256, 0, stream>>>(x, x_bf, BT*EE);
  dim3 tb(32,8), tg(24,24);
  transpose_cvt_768<<<tg, tb, 0, stream>>>(Wq, WtQKV);
  transpose_cvt_768<<<tg, tb, 0, stream>>>(Wk, WtQKV + (size_t)EE*EE);
  transpose_cvt_768<<<tg, tb, 0, stream>>>(Wv, WtQKV + (size_t)2*EE*EE);
  transpose_cvt_768<<<tg, tb, 0, stream>>>(Wo, WoT);

  gemm_qkv<<<dim3(NQKV/128, BT/128), 256, 0, stream>>>(x_bf, WtQKV, bq, bk, bv, q_ws, k_ws, v_ws);
  attn_kernel<<<dim3(32*BB*HH), 256, 0, stream>>>(q_ws, k_ws, v_ws, att_out, y_ws);
  gemm_proj<<<dim3(EE/128, BT/128), 256, 0, stream>>>(y_ws, WoT, bo, y_out);
}